// Round 4
// baseline (1171.540 us; speedup 1.0000x reference)
//
#include <hip/hip_runtime.h>
#include <hip/hip_bf16.h>

// Head: causal single-head attention fwd. B=8,T=2048,C=H=1024, fp32 in.
// Outputs: out[B,T,H] fp32, wei[B,T,T] fp32 (concat in d_out).
//
// Round 4: algebraic restructure — q,k are not outputs, so
//   logit = x (Wq^T Wk) x^T:  M = Wq^T Wk (tiny), P = x M (3-pass),
//   logits = P x^T (3-pass, causal, B = already-split x).
// Replaces 316 GF-MFMA (q,k proj + qk) with 219 GF-MFMA and kills the
// q/k hi/lo HBM round-trip. P split to f16 hi/lo keeps 22 mantissa bits:
// logit err ~4e-4 << one-hot softmax budget.
//
// ws (160MB): xh xl Ph Pl vT (5 x 32MB f16). wei16 (67MB) overlays
//   xh/xl/Ph AFTER logits (dead). W-derived scratch (16MB: WqT/WkT hi/lo,
//   Wv hi(+lo scratch), MT hi/lo) lives in d_out's OUT region (64MB),
//   dead before out_kernel writes.
//
// GEMM structure (m97 ladder): 128x128x32 tiles, 256 thr = 2x2 waves of
// 4x4 16x16x32 MFMA tiles, global_load_lds(16B) staging into 16B cells
// [khalf*128+row]; frag ds_read_b128 conflict-free.
// Frag layouts (verified m89/m91): A/B[m=lane&15][k=(lane>>4)*8+j],
// C/D col=lane&15, row=(lane>>4)*4+reg.

#define BB 8
#define TT 2048
#define CC 1024
#define HH 1024
#define BT (BB * TT)

typedef _Float16 f16x8 __attribute__((ext_vector_type(8)));
typedef _Float16 f16x4 __attribute__((ext_vector_type(4)));
typedef float f32x4 __attribute__((ext_vector_type(4)));

#define AS1 __attribute__((address_space(1)))
#define AS3 __attribute__((address_space(3)))

__device__ __forceinline__ void gld16(const _Float16* g, _Float16* lds) {
    __builtin_amdgcn_global_load_lds((AS1 const unsigned int*)g,
                                     (AS3 unsigned int*)lds, 16, 0, 0);
}

// ---------------- Kernel 0a: fp32 -> f16 hi/lo split -------------------------
__global__ __launch_bounds__(256) void split_kernel(
    const float* __restrict__ src, _Float16* __restrict__ dh,
    _Float16* __restrict__ dl, int n)
{
    int i = (blockIdx.x * 256 + threadIdx.x) * 4;
    if (i >= n) return;
    float4 v = *(const float4*)(src + i);
    f16x4 h, l;
    h[0] = (_Float16)v.x; l[0] = (_Float16)(v.x - (float)h[0]);
    h[1] = (_Float16)v.y; l[1] = (_Float16)(v.y - (float)h[1]);
    h[2] = (_Float16)v.z; l[2] = (_Float16)(v.z - (float)h[2]);
    h[3] = (_Float16)v.w; l[3] = (_Float16)(v.w - (float)h[3]);
    *(f16x4*)&dh[i] = h;
    *(f16x4*)&dl[i] = l;
}

// ---------------- Kernel 0b: fp32 W[h,c] -> f16 hi/lo W^T[c,h] ---------------
__global__ __launch_bounds__(256) void splitT_kernel(
    const float* __restrict__ W, _Float16* __restrict__ th,
    _Float16* __restrict__ tl)
{
    __shared__ float L[64][65];
    const int h0 = blockIdx.x * 64;
    const int c0 = blockIdx.y * 64;
    const int tid = threadIdx.x;
    {
        const int hl = tid >> 2;
        const int cs = (tid & 3) * 16;
#pragma unroll
        for (int jj = 0; jj < 16; jj += 4) {
            float4 v = *(const float4*)&W[(size_t)(h0 + hl) * CC + c0 + cs + jj];
            L[cs + jj + 0][hl] = v.x;
            L[cs + jj + 1][hl] = v.y;
            L[cs + jj + 2][hl] = v.z;
            L[cs + jj + 3][hl] = v.w;
        }
    }
    __syncthreads();
    const int c  = tid >> 2;
    const int hs = (tid & 3) * 16;
    f16x8 hv0, hv1, lv0, lv1;
#pragma unroll
    for (int i = 0; i < 8; ++i) {
        float a = L[c][hs + i], b = L[c][hs + 8 + i];
        hv0[i] = (_Float16)a; lv0[i] = (_Float16)(a - (float)hv0[i]);
        hv1[i] = (_Float16)b; lv1[i] = (_Float16)(b - (float)hv1[i]);
    }
    size_t o = (size_t)(c0 + c) * HH + h0 + hs;
    *(f16x8*)&th[o] = hv0; *(f16x8*)&th[o + 8] = hv1;
    *(f16x8*)&tl[o] = lv0; *(f16x8*)&tl[o + 8] = lv1;
}

// ---------------- Kernel 1: M^T = (WqT . WkT^T)^T, 3-pass, tiny --------------
// A = WqT[c,h] hi/lo, B = WkT[c',h] hi/lo, K = h. Writes MT[c'][c] hi/lo.
__global__ __launch_bounds__(256, 2) void mm_kernel(
    const _Float16* __restrict__ aH, const _Float16* __restrict__ aL,
    const _Float16* __restrict__ bH, const _Float16* __restrict__ bL,
    _Float16* __restrict__ mtH, _Float16* __restrict__ mtL)
{
    __shared__ _Float16 Ah[4096], Al[4096], Bh[4096], Bl[4096];

    const int n0 = blockIdx.x * 128;
    const int m0 = blockIdx.y * 128;

    const int tid  = threadIdx.x;
    const int r0   = tid & 127;
    const int k0   = tid >> 7;
    const int wave = tid >> 6;
    const int lane = tid & 63;
    const int quad = lane >> 4;
    const int lrow = lane & 15;
    const int wr   = (wave >> 1) * 64;
    const int wc   = (wave & 1) * 64;

    const size_t ga = (size_t)(m0 + r0) * HH + k0 * 8;
    const size_t gb = (size_t)(n0 + r0) * HH + k0 * 8;
    const int lds0 = tid * 8, lds1 = (tid + 256) * 8;

    f32x4 acc[4][4] = {};

    for (int kc = 0; kc < HH; kc += 32) {
        __syncthreads();
        gld16(aH + ga + kc,      &Ah[lds0]);
        gld16(aH + ga + kc + 16, &Ah[lds1]);
        gld16(aL + ga + kc,      &Al[lds0]);
        gld16(aL + ga + kc + 16, &Al[lds1]);
        gld16(bH + gb + kc,      &Bh[lds0]);
        gld16(bH + gb + kc + 16, &Bh[lds1]);
        gld16(bL + gb + kc,      &Bl[lds0]);
        gld16(bL + gb + kc + 16, &Bl[lds1]);
        __syncthreads();

        f16x8 ahf[4], alf[4], bhf[4], blf[4];
#pragma unroll
        for (int i = 0; i < 4; ++i) {
            ahf[i] = *(const f16x8*)&Ah[(quad * 128 + wr + i * 16 + lrow) * 8];
            alf[i] = *(const f16x8*)&Al[(quad * 128 + wr + i * 16 + lrow) * 8];
            bhf[i] = *(const f16x8*)&Bh[(quad * 128 + wc + i * 16 + lrow) * 8];
            blf[i] = *(const f16x8*)&Bl[(quad * 128 + wc + i * 16 + lrow) * 8];
        }
#pragma unroll
        for (int i = 0; i < 4; ++i)
#pragma unroll
            for (int j = 0; j < 4; ++j) {
                acc[i][j] = __builtin_amdgcn_mfma_f32_16x16x32_f16(ahf[i], bhf[j], acc[i][j], 0, 0, 0);
                acc[i][j] = __builtin_amdgcn_mfma_f32_16x16x32_f16(ahf[i], blf[j], acc[i][j], 0, 0, 0);
                acc[i][j] = __builtin_amdgcn_mfma_f32_16x16x32_f16(alf[i], bhf[j], acc[i][j], 0, 0, 0);
            }
    }

    // write transposed: MT[n][m], 4 consecutive m per lane -> f16x4
#pragma unroll
    for (int i = 0; i < 4; ++i)
#pragma unroll
        for (int j = 0; j < 4; ++j) {
            int mm = m0 + wr + i * 16 + quad * 4;
            int nn = n0 + wc + j * 16 + lrow;
            f16x4 ph, pl;
#pragma unroll
            for (int r = 0; r < 4; ++r) {
                float val = acc[i][j][r];
                _Float16 h = (_Float16)val;
                ph[r] = h;
                pl[r] = (_Float16)(val - (float)h);
            }
            *(f16x4*)&mtH[(size_t)nn * CC + mm] = ph;
            *(f16x4*)&mtL[(size_t)nn * CC + mm] = pl;
        }
}

// ---------------- Kernel 2: fused P = x M (3-pass) and v = x Wv^T (1-pass) ---
__global__ __launch_bounds__(256, 3) void pv_kernel(
    const _Float16* __restrict__ xh, const _Float16* __restrict__ xl,
    const _Float16* __restrict__ mtH, const _Float16* __restrict__ mtL,
    const _Float16* __restrict__ Wvh,
    _Float16* __restrict__ Ph, _Float16* __restrict__ Pl,
    _Float16* __restrict__ vT)
{
    __shared__ _Float16 Ah[4096], Al[4096], Bh[4096], Bl[4096];

    const int n0 = blockIdx.x * 128;
    const int m0 = blockIdx.y * 128;
    const int z  = blockIdx.z;                 // 0: P, 1: v

    const _Float16* Bsrc = (z == 0) ? mtH : Wvh;

    const int tid  = threadIdx.x;
    const int r0   = tid & 127;
    const int k0   = tid >> 7;
    const int wave = tid >> 6;
    const int lane = tid & 63;
    const int quad = lane >> 4;
    const int lrow = lane & 15;
    const int wr   = (wave >> 1) * 64;
    const int wc   = (wave & 1) * 64;

    const size_t ga = (size_t)(m0 + r0) * CC + k0 * 8;
    const size_t gb = (size_t)(n0 + r0) * CC + k0 * 8;
    const int lds0 = tid * 8, lds1 = (tid + 256) * 8;

    f32x4 acc[4][4] = {};

    for (int kc = 0; kc < CC; kc += 32) {
        __syncthreads();
        gld16(xh   + ga + kc,      &Ah[lds0]);
        gld16(xh   + ga + kc + 16, &Ah[lds1]);
        gld16(Bsrc + gb + kc,      &Bh[lds0]);
        gld16(Bsrc + gb + kc + 16, &Bh[lds1]);
        if (z == 0) {
            gld16(xl  + ga + kc,      &Al[lds0]);
            gld16(xl  + ga + kc + 16, &Al[lds1]);
            gld16(mtL + gb + kc,      &Bl[lds0]);
            gld16(mtL + gb + kc + 16, &Bl[lds1]);
        }
        __syncthreads();

        f16x8 ahf[4], bhf[4];
#pragma unroll
        for (int i = 0; i < 4; ++i) {
            ahf[i] = *(const f16x8*)&Ah[(quad * 128 + wr + i * 16 + lrow) * 8];
            bhf[i] = *(const f16x8*)&Bh[(quad * 128 + wc + i * 16 + lrow) * 8];
        }
        if (z == 0) {
            f16x8 alf[4], blf[4];
#pragma unroll
            for (int i = 0; i < 4; ++i) {
                alf[i] = *(const f16x8*)&Al[(quad * 128 + wr + i * 16 + lrow) * 8];
                blf[i] = *(const f16x8*)&Bl[(quad * 128 + wc + i * 16 + lrow) * 8];
            }
#pragma unroll
            for (int i = 0; i < 4; ++i)
#pragma unroll
                for (int j = 0; j < 4; ++j) {
                    acc[i][j] = __builtin_amdgcn_mfma_f32_16x16x32_f16(ahf[i], bhf[j], acc[i][j], 0, 0, 0);
                    acc[i][j] = __builtin_amdgcn_mfma_f32_16x16x32_f16(ahf[i], blf[j], acc[i][j], 0, 0, 0);
                    acc[i][j] = __builtin_amdgcn_mfma_f32_16x16x32_f16(alf[i], bhf[j], acc[i][j], 0, 0, 0);
                }
        } else {
#pragma unroll
            for (int i = 0; i < 4; ++i)
#pragma unroll
                for (int j = 0; j < 4; ++j)
                    acc[i][j] = __builtin_amdgcn_mfma_f32_16x16x32_f16(ahf[i], bhf[j], acc[i][j], 0, 0, 0);
        }
    }

    if (z == 1) {
        // vT[b][h][t]: 4 consecutive t per lane -> f16x4
#pragma unroll
        for (int i = 0; i < 4; ++i)
#pragma unroll
            for (int j = 0; j < 4; ++j) {
                int rrg = m0 + wr + i * 16 + quad * 4;
                int b   = rrg >> 11;
                int t0  = rrg & (TT - 1);
                int cc  = n0 + wc + j * 16 + lrow;
                f16x4 p;
#pragma unroll
                for (int r = 0; r < 4; ++r) p[r] = (_Float16)acc[i][j][r];
                *(f16x4*)&vT[(size_t)b * HH * TT + (size_t)cc * TT + t0] = p;
            }
    } else {
#pragma unroll
        for (int i = 0; i < 4; ++i)
#pragma unroll
            for (int j = 0; j < 4; ++j)
#pragma unroll
                for (int r = 0; r < 4; ++r) {
                    int rr = m0 + wr + i * 16 + quad * 4 + r;
                    int cc = n0 + wc + j * 16 + lrow;
                    float val = acc[i][j][r];
                    _Float16 h = (_Float16)val;
                    size_t idx = (size_t)rr * CC + cc;
                    Ph[idx] = h;
                    Pl[idx] = (_Float16)(val - (float)h);
                }
    }
}

// ---------------- Kernel 3: wei = (P x^T)/32, lower-tri 128-tiles, 3-pass ----
__global__ __launch_bounds__(256, 3) void logits_kernel(
    const _Float16* __restrict__ Ph, const _Float16* __restrict__ Pl,
    const _Float16* __restrict__ xh, const _Float16* __restrict__ xl,
    float* __restrict__ wei)
{
    const int st = blockIdx.x;
    const int tt = blockIdx.y;
    if (st > tt) return;
    const int b  = blockIdx.z;

    __shared__ _Float16 Ah[4096], Al[4096], Bh[4096], Bl[4096];

    const size_t base = (size_t)b * TT * CC;
    float* wb = wei + (size_t)b * TT * TT;
    const int m0 = tt * 128;
    const int n0 = st * 128;

    const int tid  = threadIdx.x;
    const int r0   = tid & 127;
    const int k0   = tid >> 7;
    const int wave = tid >> 6;
    const int lane = tid & 63;
    const int quad = lane >> 4;
    const int lrow = lane & 15;
    const int wr   = (wave >> 1) * 64;
    const int wc   = (wave & 1) * 64;

    const size_t ga = base + (size_t)(m0 + r0) * CC + k0 * 8;
    const size_t gb = base + (size_t)(n0 + r0) * CC + k0 * 8;
    const int lds0 = tid * 8, lds1 = (tid + 256) * 8;

    f32x4 acc[4][4] = {};

    for (int kc = 0; kc < CC; kc += 32) {
        __syncthreads();
        gld16(Ph + ga + kc,      &Ah[lds0]);
        gld16(Ph + ga + kc + 16, &Ah[lds1]);
        gld16(Pl + ga + kc,      &Al[lds0]);
        gld16(Pl + ga + kc + 16, &Al[lds1]);
        gld16(xh + gb + kc,      &Bh[lds0]);
        gld16(xh + gb + kc + 16, &Bh[lds1]);
        gld16(xl + gb + kc,      &Bl[lds0]);
        gld16(xl + gb + kc + 16, &Bl[lds1]);
        __syncthreads();

        f16x8 ahf[4], alf[4], bhf[4], blf[4];
#pragma unroll
        for (int i = 0; i < 4; ++i) {
            ahf[i] = *(const f16x8*)&Ah[(quad * 128 + wr + i * 16 + lrow) * 8];
            alf[i] = *(const f16x8*)&Al[(quad * 128 + wr + i * 16 + lrow) * 8];
            bhf[i] = *(const f16x8*)&Bh[(quad * 128 + wc + i * 16 + lrow) * 8];
            blf[i] = *(const f16x8*)&Bl[(quad * 128 + wc + i * 16 + lrow) * 8];
        }
#pragma unroll
        for (int i = 0; i < 4; ++i)
#pragma unroll
            for (int j = 0; j < 4; ++j) {
                acc[i][j] = __builtin_amdgcn_mfma_f32_16x16x32_f16(ahf[i], bhf[j], acc[i][j], 0, 0, 0);
                acc[i][j] = __builtin_amdgcn_mfma_f32_16x16x32_f16(ahf[i], blf[j], acc[i][j], 0, 0, 0);
                acc[i][j] = __builtin_amdgcn_mfma_f32_16x16x32_f16(alf[i], bhf[j], acc[i][j], 0, 0, 0);
            }
    }

    const float scale = 0.03125f;   // 1024^-0.5
#pragma unroll
    for (int i = 0; i < 4; ++i)
#pragma unroll
        for (int j = 0; j < 4; ++j)
#pragma unroll
            for (int r = 0; r < 4; ++r) {
                int rr = wr + i * 16 + quad * 4 + r;
                int cc = wc + j * 16 + lrow;
                wb[(size_t)(m0 + rr) * TT + n0 + cc] = acc[i][j][r] * scale;
            }
}

// ---------------- Kernel 4: causal softmax; writes fp32 wei + f16 wei16 ------
__global__ __launch_bounds__(256) void softmax_kernel(
    float* __restrict__ wei, _Float16* __restrict__ wei16)
{
    const int t = blockIdx.x;
    const int b = blockIdx.y;
    float* row = wei + (size_t)b * TT * TT + (size_t)t * TT;
    _Float16* row16 = wei16 + (size_t)b * TT * TT + (size_t)t * TT;
    const int n = t + 1;
    const int tid = threadIdx.x;
    const int base = tid * 8;

    float4 v0 = *(const float4*)&row[base];
    float4 v1 = *(const float4*)&row[base + 4];
    float vals[8] = {v0.x, v0.y, v0.z, v0.w, v1.x, v1.y, v1.z, v1.w};

    float mx = -INFINITY;
#pragma unroll
    for (int i = 0; i < 8; ++i) {
        if (base + i >= n) vals[i] = -INFINITY;
        mx = fmaxf(mx, vals[i]);
    }
#pragma unroll
    for (int off = 32; off > 0; off >>= 1)
        mx = fmaxf(mx, __shfl_down(mx, off));

    __shared__ float redm[4];
    __shared__ float reds[4];
    if ((tid & 63) == 0) redm[tid >> 6] = mx;
    __syncthreads();
    const float m = fmaxf(fmaxf(redm[0], redm[1]), fmaxf(redm[2], redm[3]));

    float sum = 0.f;
#pragma unroll
    for (int i = 0; i < 8; ++i) {
        vals[i] = __expf(vals[i] - m);
        sum += vals[i];
    }
#pragma unroll
    for (int off = 32; off > 0; off >>= 1)
        sum += __shfl_down(sum, off);
    if ((tid & 63) == 0) reds[tid >> 6] = sum;
    __syncthreads();
    const float inv = 1.0f / (reds[0] + reds[1] + reds[2] + reds[3]);

    f16x8 h;
#pragma unroll
    for (int i = 0; i < 8; ++i) {
        float w = vals[i] * inv;     // masked: exp(-inf)*inv = 0 exactly
        vals[i] = w;
        h[i] = (_Float16)w;
    }
    *(float4*)&row[base]     = make_float4(vals[0], vals[1], vals[2], vals[3]);
    *(float4*)&row[base + 4] = make_float4(vals[4], vals[5], vals[6], vals[7]);
    *(f16x8*)&row16[base]    = h;
}

// ---------------- Kernel 5: out = wei16 @ vT^T (NT, f16, causal K) -----------
__global__ __launch_bounds__(256, 3) void out_kernel(
    const _Float16* __restrict__ wei16, const _Float16* __restrict__ vT,
    float* __restrict__ out)
{
    const int nb = blockIdx.x;
    const int tt = blockIdx.y;
    const int b  = blockIdx.z;

    __shared__ _Float16 Ah[4096], Bh[4096];

    const _Float16* wb = wei16 + (size_t)b * TT * TT;
    const _Float16* vb = vT    + (size_t)b * HH * TT;
    float*          ob = out   + (size_t)b * TT * HH;

    const int m0 = tt * 128;
    const int n0 = nb * 128;
    const int kend = (tt + 1) * 128;  // wei16==0 above diagonal

    const int tid  = threadIdx.x;
    const int r0   = tid & 127;
    const int k0   = tid >> 7;
    const int wave = tid >> 6;
    const int lane = tid & 63;
    const int quad = lane >> 4;
    const int lrow = lane & 15;
    const int wr   = (wave >> 1) * 64;
    const int wc   = (wave & 1) * 64;

    const size_t ga = (size_t)(m0 + r0) * TT + k0 * 8;
    const size_t gb = (size_t)(n0 + r0) * TT + k0 * 8;
    const int lds0 = tid * 8, lds1 = (tid + 256) * 8;

    f32x4 acc[4][4] = {};

    for (int kc = 0; kc < kend; kc += 32) {
        __syncthreads();
        gld16(wb + ga + kc,      &Ah[lds0]);
        gld16(wb + ga + kc + 16, &Ah[lds1]);
        gld16(vb + gb + kc,      &Bh[lds0]);
        gld16(vb + gb + kc + 16, &Bh[lds1]);
        __syncthreads();

        f16x8 ahf[4], bhf[4];
#pragma unroll
        for (int i = 0; i < 4; ++i) {
            ahf[i] = *(const f16x8*)&Ah[(quad * 128 + wr + i * 16 + lrow) * 8];
            bhf[i] = *(const f16x8*)&Bh[(quad * 128 + wc + i * 16 + lrow) * 8];
        }
#pragma unroll
        for (int i = 0; i < 4; ++i)
#pragma unroll
            for (int j = 0; j < 4; ++j)
                acc[i][j] = __builtin_amdgcn_mfma_f32_16x16x32_f16(ahf[i], bhf[j], acc[i][j], 0, 0, 0);
    }

#pragma unroll
    for (int i = 0; i < 4; ++i)
#pragma unroll
        for (int j = 0; j < 4; ++j)
#pragma unroll
            for (int r = 0; r < 4; ++r) {
                int rr = wr + i * 16 + quad * 4 + r;
                int cc = wc + j * 16 + lrow;
                ob[(size_t)(m0 + rr) * HH + n0 + cc] = acc[i][j][r];
            }
}

extern "C" void kernel_launch(void* const* d_in, const int* in_sizes, int n_in,
                              void* d_out, int out_size, void* d_ws, size_t ws_size,
                              hipStream_t stream)
{
    const float* x  = (const float*)d_in[0];
    const float* Wk = (const float*)d_in[1];
    const float* Wq = (const float*)d_in[2];
    const float* Wv = (const float*)d_in[3];

    const size_t NX = (size_t)BT * CC;          // 16M
    const size_t NW = (size_t)HH * CC;          // 1M

    float* out = (float*)d_out;                 // [8,2048,1024] fp32
    float* wei = out + (size_t)BT * HH;         // [8,2048,2048] fp32

    // W-derived scratch in d_out's OUT region (64MB; dead before out_kernel)
    _Float16* WqTh = (_Float16*)out;            // [C,H]
    _Float16* WqTl = WqTh + NW;
    _Float16* WkTh = WqTl + NW;
    _Float16* WkTl = WkTh + NW;
    _Float16* Wvh  = WkTl + NW;                 // [H,C]
    _Float16* Wvl  = Wvh  + NW;                 // scratch (unused)
    _Float16* MTh  = Wvl  + NW;                 // [C,C] = M^T
    _Float16* MTl  = MTh  + NW;                 // total 16MB < 64MB

    // ws: 160MB = 5 x 32MB
    _Float16* xh = (_Float16*)d_ws;
    _Float16* xl = xh + NX;
    _Float16* Ph = xl + NX;
    _Float16* Pl = Ph + NX;
    _Float16* vT = Pl + NX;                     // [B][H][T]
    _Float16* wei16 = (_Float16*)d_ws;          // overlays xh/xl/Ph after logits

    split_kernel<<<dim3(NX / 1024), 256, 0, stream>>>(x, xh, xl, (int)NX);
    splitT_kernel<<<dim3(HH / 64, CC / 64), 256, 0, stream>>>(Wq, WqTh, WqTl);
    splitT_kernel<<<dim3(HH / 64, CC / 64), 256, 0, stream>>>(Wk, WkTh, WkTl);
    split_kernel<<<dim3(NW / 1024), 256, 0, stream>>>(Wv, Wvh, Wvl, (int)NW);

    mm_kernel<<<dim3(CC / 128, CC / 128), 256, 0, stream>>>(
        WqTh, WqTl, WkTh, WkTl, MTh, MTl);
    pv_kernel<<<dim3(CC / 128, BT / 128, 2), 256, 0, stream>>>(
        xh, xl, MTh, MTl, Wvh, Ph, Pl, vT);
    logits_kernel<<<dim3(TT / 128, TT / 128, BB), 256, 0, stream>>>(
        Ph, Pl, xh, xl, wei);
    softmax_kernel<<<dim3(TT, BB), 256, 0, stream>>>(wei, wei16);
    out_kernel<<<dim3(HH / 128, TT / 128, BB), 256, 0, stream>>>(wei16, vT, out);
}

// Round 5
// 1004.755 us; speedup vs baseline: 1.1660x; 1.1660x over previous
//
#include <hip/hip_runtime.h>
#include <hip/hip_bf16.h>

// Head: causal single-head attention fwd. B=8,T=2048,C=H=1024, fp32 in.
// Outputs: out[B,T,H] fp32, wei[B,T,T] fp32 (concat in d_out).
//
// Round 5: fix pv_kernel's traffic leaks found in R4 counters
// (WRITE 655MB vs 96 logical, FETCH 510 vs ~80 ideal):
//   (a) epilogues stage the 128x128 tile in LDS (stride 136, <=2-way
//       aliasing = free) then store f16x8 fully coalesced;
//   (b) XCD-strip swizzle: blocks idx&7==xcd sweep one m-strip across all
//       n-tiles -> A fetched once per XCD, reused in L2; B is L3-resident.
// Algebra unchanged from R4: M = Wq^T Wk, P = x M (3-pass f16 hi/lo),
// logits = P x^T (3-pass, causal), v 1-pass, out = wei16 @ vT^T.
//
// ws (160MB): xh xl Ph Pl vT (5 x 32MB f16); wei16 overlays xh/xl/Ph after
// logits. W-derived scratch (16MB) in d_out's OUT region, dead before
// out_kernel writes.

#define BB 8
#define TT 2048
#define CC 1024
#define HH 1024
#define BT (BB * TT)

typedef _Float16 f16x8 __attribute__((ext_vector_type(8)));
typedef _Float16 f16x4 __attribute__((ext_vector_type(4)));
typedef float f32x4 __attribute__((ext_vector_type(4)));

#define AS1 __attribute__((address_space(1)))
#define AS3 __attribute__((address_space(3)))

__device__ __forceinline__ void gld16(const _Float16* g, _Float16* lds) {
    __builtin_amdgcn_global_load_lds((AS1 const unsigned int*)g,
                                     (AS3 unsigned int*)lds, 16, 0, 0);
}

// ---------------- Kernel 0a: fp32 -> f16 hi/lo split -------------------------
__global__ __launch_bounds__(256) void split_kernel(
    const float* __restrict__ src, _Float16* __restrict__ dh,
    _Float16* __restrict__ dl, int n)
{
    int i = (blockIdx.x * 256 + threadIdx.x) * 4;
    if (i >= n) return;
    float4 v = *(const float4*)(src + i);
    f16x4 h, l;
    h[0] = (_Float16)v.x; l[0] = (_Float16)(v.x - (float)h[0]);
    h[1] = (_Float16)v.y; l[1] = (_Float16)(v.y - (float)h[1]);
    h[2] = (_Float16)v.z; l[2] = (_Float16)(v.z - (float)h[2]);
    h[3] = (_Float16)v.w; l[3] = (_Float16)(v.w - (float)h[3]);
    *(f16x4*)&dh[i] = h;
    *(f16x4*)&dl[i] = l;
}

// ---------------- Kernel 0b: fp32 W[h,c] -> f16 hi/lo W^T[c,h] ---------------
__global__ __launch_bounds__(256) void splitT_kernel(
    const float* __restrict__ W, _Float16* __restrict__ th,
    _Float16* __restrict__ tl)
{
    __shared__ float L[64][65];
    const int h0 = blockIdx.x * 64;
    const int c0 = blockIdx.y * 64;
    const int tid = threadIdx.x;
    {
        const int hl = tid >> 2;
        const int cs = (tid & 3) * 16;
#pragma unroll
        for (int jj = 0; jj < 16; jj += 4) {
            float4 v = *(const float4*)&W[(size_t)(h0 + hl) * CC + c0 + cs + jj];
            L[cs + jj + 0][hl] = v.x;
            L[cs + jj + 1][hl] = v.y;
            L[cs + jj + 2][hl] = v.z;
            L[cs + jj + 3][hl] = v.w;
        }
    }
    __syncthreads();
    const int c  = tid >> 2;
    const int hs = (tid & 3) * 16;
    f16x8 hv0, hv1, lv0, lv1;
#pragma unroll
    for (int i = 0; i < 8; ++i) {
        float a = L[c][hs + i], b = L[c][hs + 8 + i];
        hv0[i] = (_Float16)a; lv0[i] = (_Float16)(a - (float)hv0[i]);
        hv1[i] = (_Float16)b; lv1[i] = (_Float16)(b - (float)hv1[i]);
    }
    size_t o = (size_t)(c0 + c) * HH + h0 + hs;
    *(f16x8*)&th[o] = hv0; *(f16x8*)&th[o + 8] = hv1;
    *(f16x8*)&tl[o] = lv0; *(f16x8*)&tl[o + 8] = lv1;
}

// ---------------- Kernel 1: M^T = (WqT . WkT^T)^T, 3-pass, tiny --------------
__global__ __launch_bounds__(256, 2) void mm_kernel(
    const _Float16* __restrict__ aH, const _Float16* __restrict__ aL,
    const _Float16* __restrict__ bH, const _Float16* __restrict__ bL,
    _Float16* __restrict__ mtH, _Float16* __restrict__ mtL)
{
    __shared__ _Float16 Ah[4096], Al[4096], Bh[4096], Bl[4096];

    const int n0 = blockIdx.x * 128;
    const int m0 = blockIdx.y * 128;

    const int tid  = threadIdx.x;
    const int r0   = tid & 127;
    const int k0   = tid >> 7;
    const int wave = tid >> 6;
    const int lane = tid & 63;
    const int quad = lane >> 4;
    const int lrow = lane & 15;
    const int wr   = (wave >> 1) * 64;
    const int wc   = (wave & 1) * 64;

    const size_t ga = (size_t)(m0 + r0) * HH + k0 * 8;
    const size_t gb = (size_t)(n0 + r0) * HH + k0 * 8;
    const int lds0 = tid * 8, lds1 = (tid + 256) * 8;

    f32x4 acc[4][4] = {};

    for (int kc = 0; kc < HH; kc += 32) {
        __syncthreads();
        gld16(aH + ga + kc,      &Ah[lds0]);
        gld16(aH + ga + kc + 16, &Ah[lds1]);
        gld16(aL + ga + kc,      &Al[lds0]);
        gld16(aL + ga + kc + 16, &Al[lds1]);
        gld16(bH + gb + kc,      &Bh[lds0]);
        gld16(bH + gb + kc + 16, &Bh[lds1]);
        gld16(bL + gb + kc,      &Bl[lds0]);
        gld16(bL + gb + kc + 16, &Bl[lds1]);
        __syncthreads();

        f16x8 ahf[4], alf[4], bhf[4], blf[4];
#pragma unroll
        for (int i = 0; i < 4; ++i) {
            ahf[i] = *(const f16x8*)&Ah[(quad * 128 + wr + i * 16 + lrow) * 8];
            alf[i] = *(const f16x8*)&Al[(quad * 128 + wr + i * 16 + lrow) * 8];
            bhf[i] = *(const f16x8*)&Bh[(quad * 128 + wc + i * 16 + lrow) * 8];
            blf[i] = *(const f16x8*)&Bl[(quad * 128 + wc + i * 16 + lrow) * 8];
        }
#pragma unroll
        for (int i = 0; i < 4; ++i)
#pragma unroll
            for (int j = 0; j < 4; ++j) {
                acc[i][j] = __builtin_amdgcn_mfma_f32_16x16x32_f16(ahf[i], bhf[j], acc[i][j], 0, 0, 0);
                acc[i][j] = __builtin_amdgcn_mfma_f32_16x16x32_f16(ahf[i], blf[j], acc[i][j], 0, 0, 0);
                acc[i][j] = __builtin_amdgcn_mfma_f32_16x16x32_f16(alf[i], bhf[j], acc[i][j], 0, 0, 0);
            }
    }

    // write transposed: MT[n][m], 4 consecutive m per lane -> f16x4
#pragma unroll
    for (int i = 0; i < 4; ++i)
#pragma unroll
        for (int j = 0; j < 4; ++j) {
            int mm = m0 + wr + i * 16 + quad * 4;
            int nn = n0 + wc + j * 16 + lrow;
            f16x4 ph, pl;
#pragma unroll
            for (int r = 0; r < 4; ++r) {
                float val = acc[i][j][r];
                _Float16 h = (_Float16)val;
                ph[r] = h;
                pl[r] = (_Float16)(val - (float)h);
            }
            *(f16x4*)&mtH[(size_t)nn * CC + mm] = ph;
            *(f16x4*)&mtL[(size_t)nn * CC + mm] = pl;
        }
}

// ---------------- Kernel 2: fused P = x M (3-pass) and v = x Wv^T (1-pass) ---
// 1-D grid 2048, XCD-strip swizzle; LDS-staged coalesced epilogues.
#define EPI_STRIDE 136   // 128 + 8 pad: quad rows land 4 banks apart
__global__ __launch_bounds__(256, 3) void pv_kernel(
    const _Float16* __restrict__ xh, const _Float16* __restrict__ xl,
    const _Float16* __restrict__ mtH, const _Float16* __restrict__ mtL,
    const _Float16* __restrict__ Wvh,
    _Float16* __restrict__ Ph, _Float16* __restrict__ Pl,
    _Float16* __restrict__ vT)
{
    __shared__ _Float16 SM[17408];   // 4x4096 staging; epilogue 128x136
    _Float16* Ah = SM;
    _Float16* Al = SM + 4096;
    _Float16* Bh = SM + 8192;
    _Float16* Bl = SM + 12288;

    // swizzle: idx&7 = XCD; each XCD sweeps a 16-m-tile strip, n inner.
    const int idx   = blockIdx.x;
    const int z     = idx >> 10;               // 0: P, 1: v
    const int r     = idx & 1023;
    const int xcd   = r & 7;
    const int j7    = r >> 3;                  // 0..127
    const int mtile = xcd * 16 + (j7 >> 3);    // 0..127
    const int ntile = j7 & 7;                  // 0..7
    const int m0 = mtile * 128;
    const int n0 = ntile * 128;

    const _Float16* Bsrc = (z == 0) ? mtH : Wvh;

    const int tid  = threadIdx.x;
    const int r0   = tid & 127;
    const int k0   = tid >> 7;
    const int wave = tid >> 6;
    const int lane = tid & 63;
    const int quad = lane >> 4;
    const int lrow = lane & 15;
    const int wr   = (wave >> 1) * 64;
    const int wc   = (wave & 1) * 64;

    const size_t ga = (size_t)(m0 + r0) * CC + k0 * 8;
    const size_t gb = (size_t)(n0 + r0) * CC + k0 * 8;
    const int lds0 = tid * 8, lds1 = (tid + 256) * 8;

    f32x4 acc[4][4] = {};

    for (int kc = 0; kc < CC; kc += 32) {
        __syncthreads();
        gld16(xh   + ga + kc,      &Ah[lds0]);
        gld16(xh   + ga + kc + 16, &Ah[lds1]);
        gld16(Bsrc + gb + kc,      &Bh[lds0]);
        gld16(Bsrc + gb + kc + 16, &Bh[lds1]);
        if (z == 0) {
            gld16(xl  + ga + kc,      &Al[lds0]);
            gld16(xl  + ga + kc + 16, &Al[lds1]);
            gld16(mtL + gb + kc,      &Bl[lds0]);
            gld16(mtL + gb + kc + 16, &Bl[lds1]);
        }
        __syncthreads();

        f16x8 ahf[4], bhf[4];
#pragma unroll
        for (int i = 0; i < 4; ++i) {
            ahf[i] = *(const f16x8*)&Ah[(quad * 128 + wr + i * 16 + lrow) * 8];
            bhf[i] = *(const f16x8*)&Bh[(quad * 128 + wc + i * 16 + lrow) * 8];
        }
        if (z == 0) {
            f16x8 alf[4], blf[4];
#pragma unroll
            for (int i = 0; i < 4; ++i) {
                alf[i] = *(const f16x8*)&Al[(quad * 128 + wr + i * 16 + lrow) * 8];
                blf[i] = *(const f16x8*)&Bl[(quad * 128 + wc + i * 16 + lrow) * 8];
            }
#pragma unroll
            for (int i = 0; i < 4; ++i)
#pragma unroll
                for (int j = 0; j < 4; ++j) {
                    acc[i][j] = __builtin_amdgcn_mfma_f32_16x16x32_f16(ahf[i], bhf[j], acc[i][j], 0, 0, 0);
                    acc[i][j] = __builtin_amdgcn_mfma_f32_16x16x32_f16(ahf[i], blf[j], acc[i][j], 0, 0, 0);
                    acc[i][j] = __builtin_amdgcn_mfma_f32_16x16x32_f16(alf[i], bhf[j], acc[i][j], 0, 0, 0);
                }
        } else {
#pragma unroll
            for (int i = 0; i < 4; ++i)
#pragma unroll
                for (int j = 0; j < 4; ++j)
                    acc[i][j] = __builtin_amdgcn_mfma_f32_16x16x32_f16(ahf[i], bhf[j], acc[i][j], 0, 0, 0);
        }
    }

    if (z == 1) {
        // stage vT tile [h_local][t_local] in LDS, then coalesced f16x8 stores
        __syncthreads();
#pragma unroll
        for (int i = 0; i < 4; ++i)
#pragma unroll
            for (int j = 0; j < 4; ++j) {
                int hl = wc + j * 16 + lrow;
                int tl = wr + i * 16 + quad * 4;
                f16x4 p;
#pragma unroll
                for (int rr = 0; rr < 4; ++rr) p[rr] = (_Float16)acc[i][j][rr];
                *(f16x4*)&SM[hl * EPI_STRIDE + tl] = p;
            }
        __syncthreads();
        const int bi  = mtile >> 4;            // batch of this m-strip
        const int t0g = (mtile & 15) * 128;
        _Float16* vb = vT + (size_t)bi * HH * TT;
#pragma unroll
        for (int rr = 0; rr < 128; rr += 16) {
            int h = rr + (tid >> 4);
            int t = (tid & 15) * 8;
            f16x8 val = *(const f16x8*)&SM[h * EPI_STRIDE + t];
            *(f16x8*)&vb[(size_t)(n0 + h) * TT + t0g + t] = val;
        }
    } else {
        // pass 1: hi tile staged [t_local][c_local], coalesced store
        __syncthreads();
#pragma unroll
        for (int i = 0; i < 4; ++i)
#pragma unroll
            for (int j = 0; j < 4; ++j) {
                int tl = wr + i * 16 + quad * 4;
                int cl = wc + j * 16 + lrow;
#pragma unroll
                for (int rr = 0; rr < 4; ++rr)
                    SM[(tl + rr) * EPI_STRIDE + cl] = (_Float16)acc[i][j][rr];
            }
        __syncthreads();
#pragma unroll
        for (int rr = 0; rr < 128; rr += 16) {
            int t = rr + (tid >> 4);
            int c = (tid & 15) * 8;
            f16x8 val = *(const f16x8*)&SM[t * EPI_STRIDE + c];
            *(f16x8*)&Ph[(size_t)(m0 + t) * CC + n0 + c] = val;
        }
        // pass 2: lo tile
        __syncthreads();
#pragma unroll
        for (int i = 0; i < 4; ++i)
#pragma unroll
            for (int j = 0; j < 4; ++j) {
                int tl = wr + i * 16 + quad * 4;
                int cl = wc + j * 16 + lrow;
#pragma unroll
                for (int rr = 0; rr < 4; ++rr) {
                    float val = acc[i][j][rr];
                    _Float16 h = (_Float16)val;
                    SM[(tl + rr) * EPI_STRIDE + cl] = (_Float16)(val - (float)h);
                }
            }
        __syncthreads();
#pragma unroll
        for (int rr = 0; rr < 128; rr += 16) {
            int t = rr + (tid >> 4);
            int c = (tid & 15) * 8;
            f16x8 val = *(const f16x8*)&SM[t * EPI_STRIDE + c];
            *(f16x8*)&Pl[(size_t)(m0 + t) * CC + n0 + c] = val;
        }
    }
}

// ---------------- Kernel 3: wei = (P x^T)/32, lower-tri 128-tiles, 3-pass ----
__global__ __launch_bounds__(256, 3) void logits_kernel(
    const _Float16* __restrict__ Ph, const _Float16* __restrict__ Pl,
    const _Float16* __restrict__ xh, const _Float16* __restrict__ xl,
    float* __restrict__ wei)
{
    const int st = blockIdx.x;
    const int tt = blockIdx.y;
    if (st > tt) return;
    const int b  = blockIdx.z;

    __shared__ _Float16 Ah[4096], Al[4096], Bh[4096], Bl[4096];

    const size_t base = (size_t)b * TT * CC;
    float* wb = wei + (size_t)b * TT * TT;
    const int m0 = tt * 128;
    const int n0 = st * 128;

    const int tid  = threadIdx.x;
    const int r0   = tid & 127;
    const int k0   = tid >> 7;
    const int wave = tid >> 6;
    const int lane = tid & 63;
    const int quad = lane >> 4;
    const int lrow = lane & 15;
    const int wr   = (wave >> 1) * 64;
    const int wc   = (wave & 1) * 64;

    const size_t ga = base + (size_t)(m0 + r0) * CC + k0 * 8;
    const size_t gb = base + (size_t)(n0 + r0) * CC + k0 * 8;
    const int lds0 = tid * 8, lds1 = (tid + 256) * 8;

    f32x4 acc[4][4] = {};

    for (int kc = 0; kc < CC; kc += 32) {
        __syncthreads();
        gld16(Ph + ga + kc,      &Ah[lds0]);
        gld16(Ph + ga + kc + 16, &Ah[lds1]);
        gld16(Pl + ga + kc,      &Al[lds0]);
        gld16(Pl + ga + kc + 16, &Al[lds1]);
        gld16(xh + gb + kc,      &Bh[lds0]);
        gld16(xh + gb + kc + 16, &Bh[lds1]);
        gld16(xl + gb + kc,      &Bl[lds0]);
        gld16(xl + gb + kc + 16, &Bl[lds1]);
        __syncthreads();

        f16x8 ahf[4], alf[4], bhf[4], blf[4];
#pragma unroll
        for (int i = 0; i < 4; ++i) {
            ahf[i] = *(const f16x8*)&Ah[(quad * 128 + wr + i * 16 + lrow) * 8];
            alf[i] = *(const f16x8*)&Al[(quad * 128 + wr + i * 16 + lrow) * 8];
            bhf[i] = *(const f16x8*)&Bh[(quad * 128 + wc + i * 16 + lrow) * 8];
            blf[i] = *(const f16x8*)&Bl[(quad * 128 + wc + i * 16 + lrow) * 8];
        }
#pragma unroll
        for (int i = 0; i < 4; ++i)
#pragma unroll
            for (int j = 0; j < 4; ++j) {
                acc[i][j] = __builtin_amdgcn_mfma_f32_16x16x32_f16(ahf[i], bhf[j], acc[i][j], 0, 0, 0);
                acc[i][j] = __builtin_amdgcn_mfma_f32_16x16x32_f16(ahf[i], blf[j], acc[i][j], 0, 0, 0);
                acc[i][j] = __builtin_amdgcn_mfma_f32_16x16x32_f16(alf[i], bhf[j], acc[i][j], 0, 0, 0);
            }
    }

    const float scale = 0.03125f;   // 1024^-0.5
#pragma unroll
    for (int i = 0; i < 4; ++i)
#pragma unroll
        for (int j = 0; j < 4; ++j)
#pragma unroll
            for (int r = 0; r < 4; ++r) {
                int rr = wr + i * 16 + quad * 4 + r;
                int cc = wc + j * 16 + lrow;
                wb[(size_t)(m0 + rr) * TT + n0 + cc] = acc[i][j][r] * scale;
            }
}

// ---------------- Kernel 4: causal softmax; writes fp32 wei + f16 wei16 ------
__global__ __launch_bounds__(256) void softmax_kernel(
    float* __restrict__ wei, _Float16* __restrict__ wei16)
{
    const int t = blockIdx.x;
    const int b = blockIdx.y;
    float* row = wei + (size_t)b * TT * TT + (size_t)t * TT;
    _Float16* row16 = wei16 + (size_t)b * TT * TT + (size_t)t * TT;
    const int n = t + 1;
    const int tid = threadIdx.x;
    const int base = tid * 8;

    float4 v0 = *(const float4*)&row[base];
    float4 v1 = *(const float4*)&row[base + 4];
    float vals[8] = {v0.x, v0.y, v0.z, v0.w, v1.x, v1.y, v1.z, v1.w};

    float mx = -INFINITY;
#pragma unroll
    for (int i = 0; i < 8; ++i) {
        if (base + i >= n) vals[i] = -INFINITY;
        mx = fmaxf(mx, vals[i]);
    }
#pragma unroll
    for (int off = 32; off > 0; off >>= 1)
        mx = fmaxf(mx, __shfl_down(mx, off));

    __shared__ float redm[4];
    __shared__ float reds[4];
    if ((tid & 63) == 0) redm[tid >> 6] = mx;
    __syncthreads();
    const float m = fmaxf(fmaxf(redm[0], redm[1]), fmaxf(redm[2], redm[3]));

    float sum = 0.f;
#pragma unroll
    for (int i = 0; i < 8; ++i) {
        vals[i] = __expf(vals[i] - m);
        sum += vals[i];
    }
#pragma unroll
    for (int off = 32; off > 0; off >>= 1)
        sum += __shfl_down(sum, off);
    if ((tid & 63) == 0) reds[tid >> 6] = sum;
    __syncthreads();
    const float inv = 1.0f / (reds[0] + reds[1] + reds[2] + reds[3]);

    f16x8 h;
#pragma unroll
    for (int i = 0; i < 8; ++i) {
        float w = vals[i] * inv;     // masked: exp(-inf)*inv = 0 exactly
        vals[i] = w;
        h[i] = (_Float16)w;
    }
    *(float4*)&row[base]     = make_float4(vals[0], vals[1], vals[2], vals[3]);
    *(float4*)&row[base + 4] = make_float4(vals[4], vals[5], vals[6], vals[7]);
    *(f16x8*)&row16[base]    = h;
}

// ---------------- Kernel 5: out = wei16 @ vT^T (NT, f16, causal K) -----------
__global__ __launch_bounds__(256, 3) void out_kernel(
    const _Float16* __restrict__ wei16, const _Float16* __restrict__ vT,
    float* __restrict__ out)
{
    const int nb = blockIdx.x;
    const int tt = blockIdx.y;
    const int b  = blockIdx.z;

    __shared__ _Float16 Ah[4096], Bh[4096];

    const _Float16* wb = wei16 + (size_t)b * TT * TT;
    const _Float16* vb = vT    + (size_t)b * HH * TT;
    float*          ob = out   + (size_t)b * TT * HH;

    const int m0 = tt * 128;
    const int n0 = nb * 128;
    const int kend = (tt + 1) * 128;  // wei16==0 above diagonal

    const int tid  = threadIdx.x;
    const int r0   = tid & 127;
    const int k0   = tid >> 7;
    const int wave = tid >> 6;
    const int lane = tid & 63;
    const int quad = lane >> 4;
    const int lrow = lane & 15;
    const int wr   = (wave >> 1) * 64;
    const int wc   = (wave & 1) * 64;

    const size_t ga = (size_t)(m0 + r0) * TT + k0 * 8;
    const size_t gb = (size_t)(n0 + r0) * TT + k0 * 8;
    const int lds0 = tid * 8, lds1 = (tid + 256) * 8;

    f32x4 acc[4][4] = {};

    for (int kc = 0; kc < kend; kc += 32) {
        __syncthreads();
        gld16(wb + ga + kc,      &Ah[lds0]);
        gld16(wb + ga + kc + 16, &Ah[lds1]);
        gld16(vb + gb + kc,      &Bh[lds0]);
        gld16(vb + gb + kc + 16, &Bh[lds1]);
        __syncthreads();

        f16x8 ahf[4], bhf[4];
#pragma unroll
        for (int i = 0; i < 4; ++i) {
            ahf[i] = *(const f16x8*)&Ah[(quad * 128 + wr + i * 16 + lrow) * 8];
            bhf[i] = *(const f16x8*)&Bh[(quad * 128 + wc + i * 16 + lrow) * 8];
        }
#pragma unroll
        for (int i = 0; i < 4; ++i)
#pragma unroll
            for (int j = 0; j < 4; ++j)
                acc[i][j] = __builtin_amdgcn_mfma_f32_16x16x32_f16(ahf[i], bhf[j], acc[i][j], 0, 0, 0);
    }

#pragma unroll
    for (int i = 0; i < 4; ++i)
#pragma unroll
        for (int j = 0; j < 4; ++j)
#pragma unroll
            for (int r = 0; r < 4; ++r) {
                int rr = wr + i * 16 + quad * 4 + r;
                int cc = wc + j * 16 + lrow;
                ob[(size_t)(m0 + rr) * HH + n0 + cc] = acc[i][j][r];
            }
}

extern "C" void kernel_launch(void* const* d_in, const int* in_sizes, int n_in,
                              void* d_out, int out_size, void* d_ws, size_t ws_size,
                              hipStream_t stream)
{
    const float* x  = (const float*)d_in[0];
    const float* Wk = (const float*)d_in[1];
    const float* Wq = (const float*)d_in[2];
    const float* Wv = (const float*)d_in[3];

    const size_t NX = (size_t)BT * CC;          // 16M
    const size_t NW = (size_t)HH * CC;          // 1M

    float* out = (float*)d_out;                 // [8,2048,1024] fp32
    float* wei = out + (size_t)BT * HH;         // [8,2048,2048] fp32

    // W-derived scratch in d_out's OUT region (64MB; dead before out_kernel)
    _Float16* WqTh = (_Float16*)out;            // [C,H]
    _Float16* WqTl = WqTh + NW;
    _Float16* WkTh = WqTl + NW;
    _Float16* WkTl = WkTh + NW;
    _Float16* Wvh  = WkTl + NW;                 // [H,C]
    _Float16* Wvl  = Wvh  + NW;                 // scratch (unused)
    _Float16* MTh  = Wvl  + NW;                 // [C,C] = M^T
    _Float16* MTl  = MTh  + NW;                 // total 16MB < 64MB

    // ws: 160MB = 5 x 32MB
    _Float16* xh = (_Float16*)d_ws;
    _Float16* xl = xh + NX;
    _Float16* Ph = xl + NX;
    _Float16* Pl = Ph + NX;
    _Float16* vT = Pl + NX;                     // [B][H][T]
    _Float16* wei16 = (_Float16*)d_ws;          // overlays xh/xl/Ph after logits

    split_kernel<<<dim3(NX / 1024), 256, 0, stream>>>(x, xh, xl, (int)NX);
    splitT_kernel<<<dim3(HH / 64, CC / 64), 256, 0, stream>>>(Wq, WqTh, WqTl);
    splitT_kernel<<<dim3(HH / 64, CC / 64), 256, 0, stream>>>(Wk, WkTh, WkTl);
    split_kernel<<<dim3(NW / 1024), 256, 0, stream>>>(Wv, Wvh, Wvl, (int)NW);

    mm_kernel<<<dim3(CC / 128, CC / 128), 256, 0, stream>>>(
        WqTh, WqTl, WkTh, WkTl, MTh, MTl);
    pv_kernel<<<dim3(2048), 256, 0, stream>>>(
        xh, xl, MTh, MTl, Wvh, Ph, Pl, vT);
    logits_kernel<<<dim3(TT / 128, TT / 128, BB), 256, 0, stream>>>(
        Ph, Pl, xh, xl, wei);
    softmax_kernel<<<dim3(TT, BB), 256, 0, stream>>>(wei, wei16);
    out_kernel<<<dim3(HH / 128, TT / 128, BB), 256, 0, stream>>>(wei16, vT, out);
}